// Round 3
// baseline (884.799 us; speedup 1.0000x reference)
//
#include <hip/hip_runtime.h>
#include <hip/hip_bf16.h>
#include <math.h>

#define T_TOK 16384
#define DM 512
#define HID 2048
#define NE 8
#define MT 128            // tokens per expert-block
#define CH 64             // hidden per chunk
#define NCH (HID / CH)    // 32

typedef unsigned short u16;
typedef unsigned long long u64;
typedef __attribute__((ext_vector_type(4))) float f32x4;
typedef __attribute__((ext_vector_type(8))) __bf16 bf16x8;

static __device__ __forceinline__ u16 f2bf(float f) {
    __hip_bfloat16 h = __float2bfloat16(f);
    union { __hip_bfloat16 h; u16 u; } c; c.h = h; return c.u;
}

static __device__ __forceinline__ bf16x8 as_bf16x8(uint4 u) {
    union { uint4 u; bf16x8 b; } c; c.u = u; return c.b;
}

// ---------- transpose+convert: in fp32 [R][C] -> out bf16 [C][R], per expert (blockIdx.z) ----------
__global__ __launch_bounds__(256) void transpose_cvt(const float* __restrict__ in,
                                                     u16* __restrict__ out, int R, int C) {
    __shared__ float tile[64][65];
    const float* inp = in + (size_t)blockIdx.z * R * C;
    u16* outp = out + (size_t)blockIdx.z * R * C;
    int c0 = blockIdx.x * 64, r0 = blockIdx.y * 64;
    int tr = threadIdx.x >> 4;        // 0..15
    int tc = threadIdx.x & 15;        // 0..15
#pragma unroll
    for (int i = 0; i < 4; i++) {
        int r = i * 16 + tr;
        float4 v = *(const float4*)(inp + (size_t)(r0 + r) * C + c0 + tc * 4);
        tile[r][tc * 4 + 0] = v.x; tile[r][tc * 4 + 1] = v.y;
        tile[r][tc * 4 + 2] = v.z; tile[r][tc * 4 + 3] = v.w;
    }
    __syncthreads();
#pragma unroll
    for (int i = 0; i < 4; i++) {
        int c = i * 16 + tr;
        ushort4 o;
        o.x = f2bf(tile[tc * 4 + 0][c]); o.y = f2bf(tile[tc * 4 + 1][c]);
        o.z = f2bf(tile[tc * 4 + 2][c]); o.w = f2bf(tile[tc * 4 + 3][c]);
        *(ushort4*)(outp + (size_t)(c0 + c) * R + r0 + tc * 4) = o;
    }
}

// ---------------- router: fp32 logits, top-2, aggregated list append; fused x->bf16 ----------------
__global__ __launch_bounds__(256) void router_kernel(
    const float* __restrict__ x, const float* __restrict__ Wg,
    float* __restrict__ logits, int* __restrict__ cnt,
    int* __restrict__ tlist, float* __restrict__ wlist, u16* __restrict__ xb)
{
    __shared__ int   s_sel[128];
    __shared__ float s_w[128];
    const int wave = threadIdx.x >> 6, lane = threadIdx.x & 63;
    const int tbase = blockIdx.x * 64;

    for (int i = 0; i < 16; i++) {
        int ti = wave * 16 + i;
        int t  = tbase + ti;
        const float4* xp = (const float4*)(x + (size_t)t * DM) + lane * 2;
        float4 a0 = xp[0], a1 = xp[1];
        // fused x -> bf16 (each lane owns 8 consecutive elems)
        union { u16 s[8]; uint4 v; } px;
        px.s[0] = f2bf(a0.x); px.s[1] = f2bf(a0.y); px.s[2] = f2bf(a0.z); px.s[3] = f2bf(a0.w);
        px.s[4] = f2bf(a1.x); px.s[5] = f2bf(a1.y); px.s[6] = f2bf(a1.z); px.s[7] = f2bf(a1.w);
        *(uint4*)(xb + (size_t)t * DM + lane * 8) = px.v;

        float acc[NE];
#pragma unroll
        for (int e = 0; e < NE; e++) {
            const float4* wp = (const float4*)(Wg + e * DM) + lane * 2;
            float4 b0 = wp[0], b1 = wp[1];
            acc[e] = a0.x*b0.x + a0.y*b0.y + a0.z*b0.z + a0.w*b0.w
                   + a1.x*b1.x + a1.y*b1.y + a1.z*b1.z + a1.w*b1.w;
        }
#pragma unroll
        for (int e = 0; e < NE; e++) {
#pragma unroll
            for (int off = 32; off >= 1; off >>= 1)
                acc[e] += __shfl_xor(acc[e], off, 64);
        }
        if (lane == 0) {
            float4* lg = (float4*)(logits + (size_t)t * NE);
            lg[0] = make_float4(acc[0], acc[1], acc[2], acc[3]);
            lg[1] = make_float4(acc[4], acc[5], acc[6], acc[7]);
            int i0 = 0; float v0 = acc[0];
#pragma unroll
            for (int e = 1; e < NE; e++) if (acc[e] > v0) { v0 = acc[e]; i0 = e; }
            int i1 = -1; float v1 = -1e30f;
#pragma unroll
            for (int e = 0; e < NE; e++) if (e != i0 && acc[e] > v1) { v1 = acc[e]; i1 = e; }
            float w0 = 1.f / (1.f + expf(v1 - v0));   // stable 2-way softmax (v1 <= v0)
            s_sel[ti * 2] = i0; s_sel[ti * 2 + 1] = i1;
            s_w[ti * 2] = w0;   s_w[ti * 2 + 1] = 1.f - w0;
        }
    }
    __syncthreads();
    if (wave == 0) {
        int s0 = s_sel[lane * 2], s1 = s_sel[lane * 2 + 1];
        float w0 = s_w[lane * 2], w1 = s_w[lane * 2 + 1];
        u64 A = 0, B = 0, C = 0;
        int myTot = 0;
#pragma unroll
        for (int e = 0; e < NE; e++) {
            u64 q0 = __ballot(s0 == e);
            u64 q1 = __ballot(s1 == e);
            if (s0 == e) A = q0;
            if (s1 == e) { B = q0; C = q1; }
            if (lane == e) myTot = __popcll(q0) + __popcll(q1);
        }
        int base = 0;
        if (lane < NE) base = atomicAdd(&cnt[lane], myTot);
        u64 below = ((u64)1 << lane) - 1;
        int b0 = __shfl(base, s0, 64);
        int b1 = __shfl(base, s1, 64);
        int t = tbase + lane;
        int slot0 = b0 + __popcll(A & below);
        int slot1 = b1 + __popcll(B) + __popcll(C & below);
        tlist[s0 * T_TOK + slot0] = t; wlist[s0 * T_TOK + slot0] = w0;
        tlist[s1 * T_TOK + slot1] = t; wlist[s1 * T_TOK + slot1] = w1;
    }
}

// ---------------- fused expert MLP v3: M=128, XCD-pinned expert ----------------
// 1-D grid: expert = bid & 7 (rides XCD round-robin -> per-XCD L2 holds ONE expert's 4MB
// weights), tile = bid >> 3. 8 waves: GEMM1 wave=(tg:2 x hg:4) computes h chunk (64 hid);
// GEMM2 wave owns 64 out-cols x all 128 tokens. hs single-buffered (144 KB LDS total).
__global__ __launch_bounds__(512, 2) void expert_kernel(
    const u16* __restrict__ xb, const u16* __restrict__ W1T, const u16* __restrict__ W2T,
    const int* __restrict__ cnt, const int* __restrict__ tlist, const float* __restrict__ wlist,
    float* __restrict__ out)
{
    const int e = blockIdx.x & 7;
    const int tile = blockIdx.x >> 3;
    const int n = cnt[e];
    const int row0 = tile * MT;
    if (row0 >= n) return;
    const int wid = threadIdx.x >> 6;
    const int lane = threadIdx.x & 63;
    const int l15 = lane & 15, lhi = lane >> 4;
    const int tg = wid >> 2;           // GEMM1 token group (0..1)
    const int hg = wid & 3;            // GEMM1 hid group (0..3)

    __shared__ char xs[MT * 1024];     // 128 tok x 512 bf16, swizzled   (128 KB)
    __shared__ char hs[MT * CH * 2];   // 128 tok x 64 hid bf16, swizzled (16 KB)

    const int swzA = (l15 & 7) << 4;

    // ---- stage x tile (gathered rows) ----
#pragma unroll
    for (int i = 0; i < 16; i++) {
        int r = wid * 16 + i;
        int idx = row0 + r;
        int tok = (idx < n) ? tlist[e * T_TOK + idx] : 0;
        uint4 v = *(const uint4*)(xb + (size_t)tok * DM + lane * 8);
        *(uint4*)(xs + r * 1024 + ((lane * 16) ^ ((r & 7) << 4))) = v;
    }
    __syncthreads();

    f32x4 acc2[8][4];
#pragma unroll
    for (int m = 0; m < 8; m++)
#pragma unroll
        for (int nt = 0; nt < 4; nt++) acc2[m][nt] = (f32x4)0.0f;

    const u16* w1e = W1T + (size_t)e * HID * DM;   // [HID][DM]
    const u16* w2e = W2T + (size_t)e * DM * HID;   // [DM][HID]
    const u16* w1p = w1e + (size_t)(hg * 16 + l15) * DM + lhi * 8;
    const u16* w2p = w2e + (size_t)(wid * 64 + l15) * HID + lhi * 8;

    int xbase[4], hwoff[4];
#pragma unroll
    for (int m = 0; m < 4; m++) {
        int r = tg * 64 + m * 16 + l15;
        xbase[m] = r * 1024;
        hwoff[m] = r * (CH * 2) + ((hg * 32 + lhi * 8) ^ swzA);
    }
    int hbase[8];
#pragma unroll
    for (int m = 0; m < 8; m++) hbase[m] = (m * 16 + l15) * (CH * 2);

    for (int ch = 0; ch < NCH; ++ch) {
        // ---- GEMM1: h[tg tokens x (hg 16-hid)] over full K=512 ----
        f32x4 acc1[4];
#pragma unroll
        for (int m = 0; m < 4; m++) acc1[m] = (f32x4)0.0f;
        const u16* bp1 = w1p + (size_t)ch * CH * DM;
#pragma unroll
        for (int ks = 0; ks < 16; ++ks) {
            bf16x8 bw1 = *(const bf16x8*)(bp1 + ks * 32);
            int colb = ks * 64 + lhi * 16;
#pragma unroll
            for (int m = 0; m < 4; ++m) {
                bf16x8 ax = *(const bf16x8*)(xs + xbase[m] + (colb ^ swzA));
                acc1[m] = __builtin_amdgcn_mfma_f32_16x16x32_bf16(bw1, ax, acc1[m], 0, 0, 0);
            }
        }
        // ---- issue W2 fragment loads (hidden under GELU + barriers) ----
        uint4 bw2[8];
        const u16* bp2 = w2p + ch * CH;
#pragma unroll
        for (int nt = 0; nt < 4; ++nt)
#pragma unroll
            for (int k2 = 0; k2 < 2; ++k2)
                bw2[nt * 2 + k2] = *(const uint4*)(bp2 + (size_t)nt * 16 * HID + k2 * 32);
        // ---- exact-erf GELU into packed regs ----
        uint2 pk[4];
#pragma unroll
        for (int m = 0; m < 4; ++m) {
            union { ushort4 s; uint2 v; } p;
            float v0 = acc1[m][0], v1 = acc1[m][1], v2 = acc1[m][2], v3 = acc1[m][3];
            p.s.x = f2bf(0.5f * v0 * (1.0f + erff(v0 * 0.70710678f)));
            p.s.y = f2bf(0.5f * v1 * (1.0f + erff(v1 * 0.70710678f)));
            p.s.z = f2bf(0.5f * v2 * (1.0f + erff(v2 * 0.70710678f)));
            p.s.w = f2bf(0.5f * v3 * (1.0f + erff(v3 * 0.70710678f)));
            pk[m] = p.v;
        }
        __syncthreads();               // all waves done reading hs (prev chunk)
#pragma unroll
        for (int m = 0; m < 4; ++m)
            *(uint2*)(hs + hwoff[m]) = pk[m];
        __syncthreads();               // hs chunk ready
        // ---- GEMM2: acc2 += h_chunk @ W2[chunk, wid*64..+64) ----
#pragma unroll
        for (int k2 = 0; k2 < 2; ++k2) {
            int colb = k2 * 64 + lhi * 16;
            bf16x8 a2[8];
#pragma unroll
            for (int m = 0; m < 8; ++m)
                a2[m] = *(const bf16x8*)(hs + hbase[m] + (colb ^ swzA));
#pragma unroll
            for (int nt = 0; nt < 4; ++nt) {
                bf16x8 b = as_bf16x8(bw2[nt * 2 + k2]);
#pragma unroll
                for (int m = 0; m < 8; ++m)
                    acc2[m][nt] = __builtin_amdgcn_mfma_f32_16x16x32_bf16(a2[m], b, acc2[m][nt], 0, 0, 0);
            }
        }
    }

    // ---- epilogue: scale by routing weight, atomic scatter-add (skip invalid rows) ----
#pragma unroll
    for (int m = 0; m < 8; ++m) {
#pragma unroll
        for (int j = 0; j < 4; ++j) {
            int r = m * 16 + lhi * 4 + j;
            int idx = row0 + r;
            if (idx < n) {
                int tok = tlist[e * T_TOK + idx];
                float w = wlist[e * T_TOK + idx];
                float* op = out + (size_t)tok * DM + wid * 64 + l15;
#pragma unroll
                for (int nt = 0; nt < 4; ++nt)
                    atomicAdd(op + nt * 16, acc2[m][nt][j] * w);
            }
        }
    }
}

extern "C" void kernel_launch(void* const* d_in, const int* in_sizes, int n_in,
                              void* d_out, int out_size, void* d_ws, size_t ws_size,
                              hipStream_t stream) {
    const float* x  = (const float*)d_in[0];
    const float* Wg = (const float*)d_in[1];
    const float* W1 = (const float*)d_in[2];
    const float* W2 = (const float*)d_in[3];
    float* out = (float*)d_out;
    char* ws = (char*)d_ws;

    // ws layout (~50.3 MB)
    int*   cnt   = (int*)ws;                                   // 64 B
    int*   tlist = (int*)(ws + 1024);                          // 512 KB
    float* wlist = (float*)(ws + 1024 + NE * T_TOK * 4);       // 512 KB
    u16*   xb    = (u16*)(ws + (2u << 20));                    // 16 MB
    u16*   W1T   = xb + (size_t)T_TOK * DM;                    // 16 MB
    u16*   W2T   = W1T + (size_t)NE * DM * HID;                // 16 MB

    hipMemsetAsync(cnt, 0, 64, stream);
    hipMemsetAsync(out, 0, (size_t)T_TOK * DM * sizeof(float), stream);

    transpose_cvt<<<dim3(HID / 64, DM / 64, NE), 256, 0, stream>>>(W1, W1T, DM, HID);
    transpose_cvt<<<dim3(DM / 64, HID / 64, NE), 256, 0, stream>>>(W2, W2T, HID, DM);
    router_kernel<<<T_TOK / 64, 256, 0, stream>>>(x, Wg, out + (size_t)T_TOK * DM,
                                                  cnt, tlist, wlist, xb);
    expert_kernel<<<(T_TOK / MT) * NE, 512, 0, stream>>>(xb, W1T, W2T,
                                                         cnt, tlist, wlist, out);
}

// Round 4
// 647.763 us; speedup vs baseline: 1.3659x; 1.3659x over previous
//
#include <hip/hip_runtime.h>
#include <hip/hip_bf16.h>
#include <math.h>

#define T_TOK 16384
#define DM 512
#define HID 2048
#define NE 8
#define MT 64             // tokens per expert-block
#define CH 256            // hidden per chunk
#define NCH (HID / CH)    // 8 chunks -> 9 barriers/block total

typedef unsigned short u16;
typedef unsigned long long u64;
typedef __attribute__((ext_vector_type(4))) float f32x4;
typedef __attribute__((ext_vector_type(8))) __bf16 bf16x8;

static __device__ __forceinline__ u16 f2bf(float f) {
    __hip_bfloat16 h = __float2bfloat16(f);
    union { __hip_bfloat16 h; u16 u; } c; c.h = h; return c.u;
}

static __device__ __forceinline__ bf16x8 as_bf16x8(uint4 u) {
    union { uint4 u; bf16x8 b; } c; c.u = u; return c.b;
}

// ---------- transpose+convert: in fp32 [R][C] -> out bf16 [C][R], per expert (blockIdx.z) ----------
__global__ __launch_bounds__(256) void transpose_cvt(const float* __restrict__ in,
                                                     u16* __restrict__ out, int R, int C) {
    __shared__ float tile[64][65];
    const float* inp = in + (size_t)blockIdx.z * R * C;
    u16* outp = out + (size_t)blockIdx.z * R * C;
    int c0 = blockIdx.x * 64, r0 = blockIdx.y * 64;
    int tr = threadIdx.x >> 4;        // 0..15
    int tc = threadIdx.x & 15;        // 0..15
#pragma unroll
    for (int i = 0; i < 4; i++) {
        int r = i * 16 + tr;
        float4 v = *(const float4*)(inp + (size_t)(r0 + r) * C + c0 + tc * 4);
        tile[r][tc * 4 + 0] = v.x; tile[r][tc * 4 + 1] = v.y;
        tile[r][tc * 4 + 2] = v.z; tile[r][tc * 4 + 3] = v.w;
    }
    __syncthreads();
#pragma unroll
    for (int i = 0; i < 4; i++) {
        int c = i * 16 + tr;
        ushort4 o;
        o.x = f2bf(tile[tc * 4 + 0][c]); o.y = f2bf(tile[tc * 4 + 1][c]);
        o.z = f2bf(tile[tc * 4 + 2][c]); o.w = f2bf(tile[tc * 4 + 3][c]);
        *(ushort4*)(outp + (size_t)(c0 + c) * R + r0 + tc * 4) = o;
    }
}

// ---------------- router: fp32 logits, top-2, aggregated list append; fused x->bf16 ----------------
__global__ __launch_bounds__(256) void router_kernel(
    const float* __restrict__ x, const float* __restrict__ Wg,
    float* __restrict__ logits, int* __restrict__ cnt,
    int* __restrict__ tlist, float* __restrict__ wlist, u16* __restrict__ xb)
{
    __shared__ int   s_sel[128];
    __shared__ float s_w[128];
    const int wave = threadIdx.x >> 6, lane = threadIdx.x & 63;
    const int tbase = blockIdx.x * 64;

    for (int i = 0; i < 16; i++) {
        int ti = wave * 16 + i;
        int t  = tbase + ti;
        const float4* xp = (const float4*)(x + (size_t)t * DM) + lane * 2;
        float4 a0 = xp[0], a1 = xp[1];
        union { u16 s[8]; uint4 v; } px;
        px.s[0] = f2bf(a0.x); px.s[1] = f2bf(a0.y); px.s[2] = f2bf(a0.z); px.s[3] = f2bf(a0.w);
        px.s[4] = f2bf(a1.x); px.s[5] = f2bf(a1.y); px.s[6] = f2bf(a1.z); px.s[7] = f2bf(a1.w);
        *(uint4*)(xb + (size_t)t * DM + lane * 8) = px.v;

        float acc[NE];
#pragma unroll
        for (int e = 0; e < NE; e++) {
            const float4* wp = (const float4*)(Wg + e * DM) + lane * 2;
            float4 b0 = wp[0], b1 = wp[1];
            acc[e] = a0.x*b0.x + a0.y*b0.y + a0.z*b0.z + a0.w*b0.w
                   + a1.x*b1.x + a1.y*b1.y + a1.z*b1.z + a1.w*b1.w;
        }
#pragma unroll
        for (int e = 0; e < NE; e++) {
#pragma unroll
            for (int off = 32; off >= 1; off >>= 1)
                acc[e] += __shfl_xor(acc[e], off, 64);
        }
        if (lane == 0) {
            float4* lg = (float4*)(logits + (size_t)t * NE);
            lg[0] = make_float4(acc[0], acc[1], acc[2], acc[3]);
            lg[1] = make_float4(acc[4], acc[5], acc[6], acc[7]);
            int i0 = 0; float v0 = acc[0];
#pragma unroll
            for (int e = 1; e < NE; e++) if (acc[e] > v0) { v0 = acc[e]; i0 = e; }
            int i1 = -1; float v1 = -1e30f;
#pragma unroll
            for (int e = 0; e < NE; e++) if (e != i0 && acc[e] > v1) { v1 = acc[e]; i1 = e; }
            float w0 = 1.f / (1.f + expf(v1 - v0));   // stable 2-way softmax (v1 <= v0)
            s_sel[ti * 2] = i0; s_sel[ti * 2 + 1] = i1;
            s_w[ti * 2] = w0;   s_w[ti * 2 + 1] = 1.f - w0;
        }
    }
    __syncthreads();
    if (wave == 0) {
        int s0 = s_sel[lane * 2], s1 = s_sel[lane * 2 + 1];
        float w0 = s_w[lane * 2], w1 = s_w[lane * 2 + 1];
        u64 A = 0, B = 0, C = 0;
        int myTot = 0;
#pragma unroll
        for (int e = 0; e < NE; e++) {
            u64 q0 = __ballot(s0 == e);
            u64 q1 = __ballot(s1 == e);
            if (s0 == e) A = q0;
            if (s1 == e) { B = q0; C = q1; }
            if (lane == e) myTot = __popcll(q0) + __popcll(q1);
        }
        int base = 0;
        if (lane < NE) base = atomicAdd(&cnt[lane], myTot);
        u64 below = ((u64)1 << lane) - 1;
        int b0 = __shfl(base, s0, 64);
        int b1 = __shfl(base, s1, 64);
        int t = tbase + lane;
        int slot0 = b0 + __popcll(A & below);
        int slot1 = b1 + __popcll(B) + __popcll(C & below);
        tlist[s0 * T_TOK + slot0] = t; wlist[s0 * T_TOK + slot0] = w0;
        tlist[s1 * T_TOK + slot1] = t; wlist[s1 * T_TOK + slot1] = w1;
    }
}

// ---------------- fused expert MLP v4: M=64, CH=256, 9 barriers/block ----------------
// 1-D grid, expert = bid&7 (XCD-pinned -> 4MB expert weights stay in that XCD's L2).
// 8 waves: GEMM1 wave owns 32 hidden rows (no W1 duplication), all 64 tokens;
// GEMM2 wave owns 64 out-cols, all 64 tokens. hs double-buffered -> 1 barrier/chunk.
__global__ __launch_bounds__(512, 2) void expert_kernel(
    const u16* __restrict__ xb, const u16* __restrict__ W1T, const u16* __restrict__ W2T,
    const int* __restrict__ cnt, const int* __restrict__ tlist, const float* __restrict__ wlist,
    float* __restrict__ out)
{
    const int e = blockIdx.x & 7;
    const int tile = blockIdx.x >> 3;
    const int n = cnt[e];
    const int row0 = tile * MT;
    if (row0 >= n) return;
    const int wid = threadIdx.x >> 6;
    const int lane = threadIdx.x & 63;
    const int l15 = lane & 15, lhi = lane >> 4;
    const int* tl = tlist + e * T_TOK;

    __shared__ char xs[MT * 1024];        // 64 tok x 512 bf16, swizzled (64 KB)
    __shared__ char hs[2][MT * CH * 2];   // dbuf: 64 tok x 256 hid bf16, swizzled (2 x 32 KB)

    // ---- stage x tile (gathered rows), 8 rows per wave ----
#pragma unroll
    for (int i = 0; i < 8; i++) {
        int r = wid * 8 + i;
        int idx = row0 + r;
        int tok = (idx < n) ? tl[idx] : 0;
        uint4 v = *(const uint4*)(xb + (size_t)tok * DM + lane * 8);
        *(uint4*)(xs + r * 1024 + ((lane * 16) ^ ((r & 7) << 4))) = v;
    }
    __syncthreads();

    f32x4 acc2[4][4];
#pragma unroll
    for (int m = 0; m < 4; m++)
#pragma unroll
        for (int nt = 0; nt < 4; nt++) acc2[m][nt] = (f32x4)0.0f;

    const u16* w1p = W1T + (size_t)e * HID * DM + (size_t)(wid * 32 + l15) * DM + lhi * 8;
    const u16* w2p = W2T + (size_t)e * DM * HID + (size_t)(wid * 64 + l15) * HID + lhi * 8;

    int xrow[4], hrow[4], swz[4];
#pragma unroll
    for (int m = 0; m < 4; m++) {
        int r = m * 16 + l15;
        xrow[m] = r * 1024;
        hrow[m] = r * (CH * 2);
        swz[m]  = (r & 7) << 4;
    }

    for (int ch = 0; ch < NCH; ++ch) {
        // ---- GEMM1: h[64 tok x 32 hid(wid)] over K=512; W1 frags streamed from L2 ----
        f32x4 acc1[2][4];
#pragma unroll
        for (int ht = 0; ht < 2; ht++)
#pragma unroll
            for (int m = 0; m < 4; m++) acc1[ht][m] = (f32x4)0.0f;
        const u16* bp1 = w1p + (size_t)ch * CH * DM;
#pragma unroll
        for (int ks = 0; ks < 16; ++ks) {
            bf16x8 w1a = as_bf16x8(*(const uint4*)(bp1 + ks * 32));
            bf16x8 w1b = as_bf16x8(*(const uint4*)(bp1 + 16 * DM + ks * 32));
            int colb = ks * 64 + lhi * 16;
#pragma unroll
            for (int m = 0; m < 4; ++m) {
                bf16x8 bx = *(const bf16x8*)(xs + xrow[m] + (colb ^ swz[m]));
                acc1[0][m] = __builtin_amdgcn_mfma_f32_16x16x32_bf16(w1a, bx, acc1[0][m], 0, 0, 0);
                acc1[1][m] = __builtin_amdgcn_mfma_f32_16x16x32_bf16(w1b, bx, acc1[1][m], 0, 0, 0);
            }
        }
        // ---- exact-erf GELU -> packed bf16 -> hs[ch&1] (uint2 swizzled writes) ----
        char* hw = hs[ch & 1];
#pragma unroll
        for (int ht = 0; ht < 2; ++ht) {
#pragma unroll
            for (int m = 0; m < 4; ++m) {
                union { ushort4 s; uint2 v; } p;
                float v0 = acc1[ht][m][0], v1 = acc1[ht][m][1];
                float v2 = acc1[ht][m][2], v3 = acc1[ht][m][3];
                p.s.x = f2bf(0.5f * v0 * (1.0f + erff(v0 * 0.70710678f)));
                p.s.y = f2bf(0.5f * v1 * (1.0f + erff(v1 * 0.70710678f)));
                p.s.z = f2bf(0.5f * v2 * (1.0f + erff(v2 * 0.70710678f)));
                p.s.w = f2bf(0.5f * v3 * (1.0f + erff(v3 * 0.70710678f)));
                *(uint2*)(hw + hrow[m] + ((wid * 64 + ht * 32 + lhi * 8) ^ swz[m])) = p.v;
            }
        }
        __syncthreads();   // single barrier per chunk (dbuf: next chunk writes the other buffer)
        // ---- GEMM2: acc2 += h_chunk @ W2[ch*256..+256, wid*64..+64) ----
        const char* hr = hs[ch & 1];
        const u16* bp2 = w2p + ch * CH;
#pragma unroll
        for (int k2 = 0; k2 < 8; ++k2) {
            int colb = k2 * 64 + lhi * 16;
            bf16x8 a2[4];
#pragma unroll
            for (int m = 0; m < 4; ++m)
                a2[m] = *(const bf16x8*)(hr + hrow[m] + (colb ^ swz[m]));
#pragma unroll
            for (int nt = 0; nt < 4; ++nt) {
                bf16x8 b = as_bf16x8(*(const uint4*)(bp2 + (size_t)nt * 16 * HID + k2 * 32));
#pragma unroll
                for (int m = 0; m < 4; ++m)
                    acc2[m][nt] = __builtin_amdgcn_mfma_f32_16x16x32_bf16(a2[m], b, acc2[m][nt], 0, 0, 0);
            }
        }
    }

    // ---- epilogue: scale by routing weight, atomic scatter-add (skip invalid rows) ----
    const float* wl = wlist + e * T_TOK;
#pragma unroll
    for (int m = 0; m < 4; ++m) {
#pragma unroll
        for (int j = 0; j < 4; ++j) {
            int r = m * 16 + lhi * 4 + j;
            int idx = row0 + r;
            if (idx < n) {
                int tok = tl[idx];
                float w = wl[idx];
                float* op = out + (size_t)tok * DM + wid * 64 + l15;
#pragma unroll
                for (int nt = 0; nt < 4; ++nt)
                    atomicAdd(op + nt * 16, acc2[m][nt][j] * w);
            }
        }
    }
}

extern "C" void kernel_launch(void* const* d_in, const int* in_sizes, int n_in,
                              void* d_out, int out_size, void* d_ws, size_t ws_size,
                              hipStream_t stream) {
    const float* x  = (const float*)d_in[0];
    const float* Wg = (const float*)d_in[1];
    const float* W1 = (const float*)d_in[2];
    const float* W2 = (const float*)d_in[3];
    float* out = (float*)d_out;
    char* ws = (char*)d_ws;

    // ws layout (~50.3 MB)
    int*   cnt   = (int*)ws;                                   // 64 B
    int*   tlist = (int*)(ws + 1024);                          // 512 KB
    float* wlist = (float*)(ws + 1024 + NE * T_TOK * 4);       // 512 KB
    u16*   xb    = (u16*)(ws + (2u << 20));                    // 16 MB
    u16*   W1T   = xb + (size_t)T_TOK * DM;                    // 16 MB
    u16*   W2T   = W1T + (size_t)NE * DM * HID;                // 16 MB

    hipMemsetAsync(cnt, 0, 64, stream);
    hipMemsetAsync(out, 0, (size_t)T_TOK * DM * sizeof(float), stream);

    transpose_cvt<<<dim3(HID / 64, DM / 64, NE), 256, 0, stream>>>(W1, W1T, DM, HID);
    transpose_cvt<<<dim3(DM / 64, HID / 64, NE), 256, 0, stream>>>(W2, W2T, HID, DM);
    router_kernel<<<T_TOK / 64, 256, 0, stream>>>(x, Wg, out + (size_t)T_TOK * DM,
                                                  cnt, tlist, wlist, xb);
    expert_kernel<<<(T_TOK / MT) * NE, 512, 0, stream>>>(xb, W1T, W2T,
                                                         cnt, tlist, wlist, out);
}